// Round 12
// baseline (6606.023 us; speedup 1.0000x reference)
//
#include <hip/hip_runtime.h>
#include <hip/hip_bf16.h>

#define Hd 768
#define Bd 32
#define Td 1024
#define Md (Bd*Td)

// scan: 8 groups (4 batches each) x 32 slices (24 rows each) = 256 WGs
#define NGRP 8
#define SPW   32
#define RPW   24          // rows per WG
#define BPG   4           // batches per group
#define THRS  384
#define RINGD 4
#define SENT_U 0x7FC00000u
#define RVALS (BPG*Hd)    // 3072 words per ring region
#define WSTRIDE 770       // f32x2 pairs per padded weight row (768 + 2 pad)
#define SMEM_BYTES (RPW*WSTRIDE*8 + RVALS*4)   // 147840 + 12288 = 160128

typedef unsigned int u32x4 __attribute__((ext_vector_type(4)));
typedef float f32x2 __attribute__((ext_vector_type(2)));

static __device__ __forceinline__ f32x2 splat2(float v) { f32x2 r; r.x = v; r.y = v; return r; }

// ---------------- init: ring region 0 = h0, regions 1..3 = sentinel ----------------
__global__ __launch_bounds__(256) void k_init(const float* __restrict__ hid,
                                              unsigned* __restrict__ ring) {
    int i = blockIdx.x * 256 + threadIdx.x;          // 8*4*3072 = 98304 total
    const int grp = i / (RINGD * RVALS);
    const int rem = i % (RINGD * RVALS);
    const int r   = rem / RVALS;
    const int q   = rem % RVALS;
    const int bb  = q / Hd;
    const int k   = q % Hd;
    unsigned v = SENT_U;
    if (r == 0) v = ((const unsigned*)hid)[(grp * BPG + bb) * Hd + k];
    ring[i] = v;
}

// ---------------- phase 1: gi GEMM (unchanged) ----------------
__global__ __launch_bounds__(256, 2) void k_gemm(const float* __restrict__ A,
                                                 const float* __restrict__ Wih,
                                                 const float* __restrict__ bih,
                                                 float* __restrict__ giR,
                                                 float* __restrict__ giN) {
    __shared__ float As[16][68];
    __shared__ float Brs[16][68];
    __shared__ float Bns[16][68];
    const int tid = threadIdx.x;
    const int mb = blockIdx.x & 511;
    const int nb = blockIdx.x >> 9;
    const int lm = tid >> 2;
    const int lk = (tid & 3) << 2;
    const int tx = tid & 15;
    const int ty = tid >> 4;

    const float* pA = A   + (size_t)(mb * 64 + lm) * Hd + lk;
    const float* pR = Wih + (size_t)(nb * 64 + lm) * Hd + lk;
    const float* pN = Wih + (size_t)(2 * Hd + nb * 64 + lm) * Hd + lk;

    float accR[4][4] = {{0.f}};
    float accN[4][4] = {{0.f}};

    for (int kt = 0; kt < Hd; kt += 16) {
        float4 va = *(const float4*)(pA + kt);
        float4 vr = *(const float4*)(pR + kt);
        float4 vn = *(const float4*)(pN + kt);
        __syncthreads();
        As[lk+0][lm]=va.x; As[lk+1][lm]=va.y; As[lk+2][lm]=va.z; As[lk+3][lm]=va.w;
        Brs[lk+0][lm]=vr.x; Brs[lk+1][lm]=vr.y; Brs[lk+2][lm]=vr.z; Brs[lk+3][lm]=vr.w;
        Bns[lk+0][lm]=vn.x; Bns[lk+1][lm]=vn.y; Bns[lk+2][lm]=vn.z; Bns[lk+3][lm]=vn.w;
        __syncthreads();
        #pragma unroll
        for (int k = 0; k < 16; ++k) {
            float4 a4 = *(const float4*)&As[k][ty << 2];
            float4 r4 = *(const float4*)&Brs[k][tx << 2];
            float4 n4 = *(const float4*)&Bns[k][tx << 2];
            float av[4] = {a4.x, a4.y, a4.z, a4.w};
            float rv[4] = {r4.x, r4.y, r4.z, r4.w};
            float nv[4] = {n4.x, n4.y, n4.z, n4.w};
            #pragma unroll
            for (int i = 0; i < 4; ++i)
                #pragma unroll
                for (int j = 0; j < 4; ++j) {
                    accR[i][j] += av[i] * rv[j];
                    accN[i][j] += av[i] * nv[j];
                }
        }
    }

    const int m0 = mb * 64 + (ty << 2);
    const int g0 = nb * 64 + (tx << 2);
    float4 bR = *(const float4*)(bih + g0);
    float4 bN = *(const float4*)(bih + 2 * Hd + g0);
    #pragma unroll
    for (int i = 0; i < 4; ++i) {
        float4 oR = { accR[i][0]+bR.x, accR[i][1]+bR.y, accR[i][2]+bR.z, accR[i][3]+bR.w };
        float4 oN = { accN[i][0]+bN.x, accN[i][1]+bN.y, accN[i][2]+bN.z, accN[i][3]+bN.w };
        *(float4*)(giR + (size_t)(m0 + i) * Hd + g0) = oR;
        *(float4*)(giN + (size_t)(m0 + i) * Hd + g0) = oN;
    }
}

// ---------------- phase 2: sentinel-ring scan, LDS-resident weights ----
// 256 WGs = 8 groups x 32 slices; 384 threads = (gl 0..23 = row) x (ks 0..15).
// Weights: 24 rows x 768 k x {W_hr,W_hn} f32x2 pairs in dynamic LDS (147.8 KB,
// padded stride 770 -> 2-way banks = free), loaded ONCE. hs: 4x768 f32 single
// buffer (12 KB). 2 barriers/step. Protocol (R3/R8-proven): poll t -> reset own
// produce word (t+2) + gi prefetch -> barrier -> compute -> vmcnt(0) ->
// produce (t+1) -> barrier.
__global__ __launch_bounds__(THRS) void k_scan(const float* __restrict__ Whh,
                                               const float* __restrict__ bhh,
                                               const float* __restrict__ giR,
                                               float* __restrict__ out,   // giN in, h out
                                               unsigned* __restrict__ ring) {
    extern __shared__ char smem[];
    f32x2* wlds = (f32x2*)smem;                        // [RPW][WSTRIDE]
    float* hs   = (float*)(smem + RPW * WSTRIDE * 8);  // [BPG*Hd]

    const int tid = threadIdx.x;
    const int gl  = tid >> 4;          // 0..23 = local row
    const int ks  = tid & 15;          // 0..15 = k-slice
    const int grp = blockIdx.x >> 5;   // 0..7
    const int s   = blockIdx.x & 31;   // 0..31
    const int b0  = grp * BPG;
    const int g   = s * RPW + gl;      // global row 0..767
    unsigned* ringp = ring + (size_t)grp * RINGD * RVALS;

    // ---- one-time: stage weights into LDS as {W_hr, W_hn} pairs ----
    #pragma unroll
    for (int j = 0; j < 12; ++j) {
        const int kb = (ks << 2) + (j << 6);
        float4 a = *(const float4*)(Whh + (size_t)g * Hd + kb);
        float4 b = *(const float4*)(Whh + (size_t)(2 * Hd + g) * Hd + kb);
        f32x2* wp = wlds + gl * WSTRIDE + kb;
        f32x2 p0; p0.x = a.x; p0.y = b.x;
        f32x2 p1; p1.x = a.y; p1.y = b.y;
        f32x2 p2; p2.x = a.z; p2.y = b.z;
        f32x2 p3; p3.x = a.w; p3.y = b.w;
        wp[0] = p0; wp[1] = p1; wp[2] = p2; wp[3] = p3;
    }

    // per-output-lane state: lanes ks<4 own (row g, batch bb=ks)
    const int obb = ks;                 // valid when ks<4
    float obr = 0.f, obn = 0.f, gRv = 0.f, gNv = 0.f;
    if (ks < 4) {
        obr = bhh[g];
        obn = bhh[2 * Hd + g];
        const size_t mi = ((size_t)(b0 + obb) * Td) * Hd + g;
        gRv = giR[mi];
        gNv = out[mi];
    }
    __syncthreads();   // weights staged

    for (int t = 0; t < Td; ++t) {
        // ---- poll own 8 words (2 dwordx4) of region t%4 ----
        const unsigned* myp = ringp + (t & 3) * RVALS + (tid << 3);
        u32x4 w0, w1;
        asm volatile(
            "global_load_dwordx4 %0, %2, off sc0 sc1\n\t"
            "global_load_dwordx4 %1, %3, off sc0 sc1\n\t"
            "s_waitcnt vmcnt(0)"
            : "=&v"(w0), "=&v"(w1) : "v"(myp), "v"(myp + 4) : "memory");
        while (w0.x == SENT_U || w0.y == SENT_U || w0.z == SENT_U || w0.w == SENT_U ||
               w1.x == SENT_U || w1.y == SENT_U || w1.z == SENT_U || w1.w == SENT_U) {
            __builtin_amdgcn_s_sleep(1);
            asm volatile(
                "global_load_dwordx4 %0, %2, off sc0 sc1\n\t"
                "global_load_dwordx4 %1, %3, off sc0 sc1\n\t"
                "s_waitcnt vmcnt(0)"
                : "=&v"(w0), "=&v"(w1) : "v"(myp), "v"(myp + 4) : "memory");
        }
        *(u32x4*)((unsigned*)hs + (tid << 3))     = w0;
        *(u32x4*)((unsigned*)hs + (tid << 3) + 4) = w1;

        // ---- reset own produce word in region (t+2)%4 + gi prefetch t+1 ----
        float gR2 = 0.f, gN2 = 0.f;
        if (ks < 4) {
            const unsigned* rp = ringp + ((t + 2) & 3) * RVALS + obb * Hd + g;
            unsigned sv = SENT_U;
            asm volatile("global_store_dword %0, %1, off sc0 sc1"
                         :: "v"(rp), "v"(sv) : "memory");
            if (t + 1 < Td) {
                const size_t mi = ((size_t)(b0 + obb) * Td + (t + 1)) * Hd + g;
                gR2 = giR[mi];
                gN2 = out[mi];
            }
        }

        __syncthreads();   // hs staged

        // ---- matvec: row gl, k-slice ks, 4 batches, packed {R,N} ----
        f32x2 a0 = splat2(0.f), a1 = splat2(0.f), a2 = splat2(0.f), a3 = splat2(0.f);
        #pragma unroll
        for (int j = 0; j < 12; ++j) {
            const int kb = (ks << 2) + (j << 6);
            const f32x2* wp = wlds + gl * WSTRIDE + kb;
            const f32x2 q0 = wp[0], q1 = wp[1], q2 = wp[2], q3 = wp[3];
            float4 h0 = *(const float4*)&hs[0 * Hd + kb];
            float4 h1 = *(const float4*)&hs[1 * Hd + kb];
            float4 h2 = *(const float4*)&hs[2 * Hd + kb];
            float4 h3 = *(const float4*)&hs[3 * Hd + kb];
            a0 = __builtin_elementwise_fma(splat2(h0.x), q0, a0);
            a0 = __builtin_elementwise_fma(splat2(h0.y), q1, a0);
            a0 = __builtin_elementwise_fma(splat2(h0.z), q2, a0);
            a0 = __builtin_elementwise_fma(splat2(h0.w), q3, a0);
            a1 = __builtin_elementwise_fma(splat2(h1.x), q0, a1);
            a1 = __builtin_elementwise_fma(splat2(h1.y), q1, a1);
            a1 = __builtin_elementwise_fma(splat2(h1.z), q2, a1);
            a1 = __builtin_elementwise_fma(splat2(h1.w), q3, a1);
            a2 = __builtin_elementwise_fma(splat2(h2.x), q0, a2);
            a2 = __builtin_elementwise_fma(splat2(h2.y), q1, a2);
            a2 = __builtin_elementwise_fma(splat2(h2.z), q2, a2);
            a2 = __builtin_elementwise_fma(splat2(h2.w), q3, a2);
            a3 = __builtin_elementwise_fma(splat2(h3.x), q0, a3);
            a3 = __builtin_elementwise_fma(splat2(h3.y), q1, a3);
            a3 = __builtin_elementwise_fma(splat2(h3.z), q2, a3);
            a3 = __builtin_elementwise_fma(splat2(h3.w), q3, a3);
        }
        // butterfly over the 16 ks lanes (per component)
        #pragma unroll
        for (int off = 8; off >= 1; off >>= 1) {
            a0.x += __shfl_xor(a0.x, off); a0.y += __shfl_xor(a0.y, off);
            a1.x += __shfl_xor(a1.x, off); a1.y += __shfl_xor(a1.y, off);
            a2.x += __shfl_xor(a2.x, off); a2.y += __shfl_xor(a2.y, off);
            a3.x += __shfl_xor(a3.x, off); a3.y += __shfl_xor(a3.y, off);
        }

        // ---- epilogue on lanes ks<4 (batch = ks; static select) ----
        float hnew = 0.f;
        if (ks < 4) {
            f32x2 mine = (ks & 2) ? ((ks & 1) ? a3 : a2) : ((ks & 1) ? a1 : a0);
            const float r = 1.f / (1.f + __expf(-(gRv + mine.x + obr)));
            hnew = tanhf(gNv + r * (mine.y + obn));
            gRv = gR2; gNv = gN2;
        }

        // ---- order reset ack (and gi prefetch) before produce ----
        asm volatile("s_waitcnt vmcnt(0)" ::: "memory");

        // ---- produce h_{t+1} word + out[:,t] ----
        if (ks < 4) {
            const unsigned* dp = ringp + ((t + 1) & 3) * RVALS + obb * Hd + g;
            const unsigned hbits = __float_as_uint(hnew);
            asm volatile("global_store_dword %0, %1, off sc0 sc1"
                         :: "v"(dp), "v"(hbits) : "memory");
            out[((size_t)(b0 + obb) * Td + t) * Hd + g] = hnew;
        }

        __syncthreads();   // all hs reads done before next-iter overwrite
    }
}

extern "C" void kernel_launch(void* const* d_in, const int* in_sizes, int n_in,
                              void* d_out, int out_size, void* d_ws, size_t ws_size,
                              hipStream_t stream) {
    const float* input  = (const float*)d_in[0];
    const float* hidden = (const float*)d_in[1];
    const float* Wih    = (const float*)d_in[2];
    const float* Whh    = (const float*)d_in[3];
    const float* bih    = (const float*)d_in[4];
    const float* bhh    = (const float*)d_in[5];
    float* out = (float*)d_out;

    float*    giR  = (float*)d_ws;
    unsigned* ring = (unsigned*)(giR + (size_t)Md * Hd);

    // allow >64KB dynamic LDS for k_scan (idempotent; not a stream op)
    hipFuncSetAttribute((const void*)k_scan,
                        hipFuncAttributeMaxDynamicSharedMemorySize, SMEM_BYTES);

    k_init<<<(NGRP * RINGD * RVALS) / 256, 256, 0, stream>>>(hidden, ring);
    k_gemm<<<512 * 12, 256, 0, stream>>>(input, Wih, bih, giR, out);
    k_scan<<<NGRP * SPW, THRS, SMEM_BYTES, stream>>>(Whh, bhh, giR, out, ring);
}